// Round 5
// baseline (307.034 us; speedup 1.0000x reference)
//
#include <hip/hip_runtime.h>
#include <math.h>

#define NTOT 4608          // N_IN * DIM * DIM

typedef _Float16 f16;
typedef _Float16 f16x8 __attribute__((ext_vector_type(8)));
typedef float f32x4 __attribute__((ext_vector_type(4)));

// ---- ut[b][n][d] f16 <- x[b][d][n] f32
__global__ __launch_bounds__(256) void make_ut(const float* __restrict__ x, f16* __restrict__ ut) {
    const int t = blockIdx.x * 256 + threadIdx.x;     // b*4608 + n
    const int b = t / NTOT, n = t - b * NTOT;
    f16x8 v;
    #pragma unroll
    for (int d = 0; d < 8; ++d)
        v[d] = (f16)x[((size_t)b * 8 + d) * NTOT + n];
    *reinterpret_cast<f16x8*>(ut + (size_t)t * 8) = v;
}

// ---- wt[n][j*16+o][d] f16 <- W[d][o][n][j] f32, LDS-staged for coalescing.
__global__ __launch_bounds__(320) void make_wt(const float* __restrict__ W, f16* __restrict__ wt) {
    __shared__ float l[2560];
    const int k = threadIdx.x;           // 0..319
    const int n0 = blockIdx.x * 2;
    #pragma unroll
    for (int r = 0; r < 8; ++r) {
        const int f = k + r * 320;
        const int p = f / 20, q = f - p * 20;
        l[f] = W[(size_t)p * 46080 + n0 * 10 + q];
    }
    __syncthreads();
    const int half = k / 160, rr = k - half * 160;    // rr = j*16 + o
    const int j = rr >> 4, o = rr & 15;
    f16x8 v;
    #pragma unroll
    for (int d = 0; d < 8; ++d)
        v[d] = (f16)l[d * 320 + o * 20 + half * 10 + j];
    *reinterpret_cast<f16x8*>(wt + ((size_t)(n0 + half) * 160 + rr) * 8) = v;
}

// ---- fused routing iteration.
// Wave: 16 b (MFMA cols) x 4 n. MFMA m: A rows = o, j = m. K-duplicated frags
// (all 4 k-groups load the same 8 halves) -> C = 4*u_hat; folded via Ar = A/4
// and phase2 sumscale 0.25. Cross-wave (4 n-subsets) reduce via LDS, then one
// partial tile per (chunk, 16b-group).
template<bool FIRST>
__global__ __launch_bounds__(256) void routing(const f16* __restrict__ ut,
                                               const f16* __restrict__ wt,
                                               const float* __restrict__ Ar,
                                               float* __restrict__ partial) {
    __shared__ float s1t[4][16][160];
    const int tid = threadIdx.x;
    const int w = tid >> 6, lane = tid & 63;
    const int col = lane & 15, kg = lane >> 4;
    const int chunk = blockIdx.x, bg = blockIdx.y;
    const int b = bg * 16 + col;
    const int n0 = chunk * 16 + w * 4;
    const f16* ub = ut + ((size_t)b * NTOT + n0) * 8;
    const f16* wb = wt + ((size_t)n0 * 160 + col) * 8;
    const f32x4 cz = {0.f, 0.f, 0.f, 0.f};

    float c[4][10];
    if (!FIRST) {
        float A4[10][4];
        #pragma unroll
        for (int m = 0; m < 10; ++m) {
            f32x4 v = *reinterpret_cast<const f32x4*>(Ar + (size_t)b * 160 + m * 16 + kg * 4);
            #pragma unroll
            for (int i = 0; i < 4; ++i) A4[m][i] = v[i];
        }
        #pragma unroll
        for (int nl = 0; nl < 4; ++nl) {
            const f16x8 bf = *reinterpret_cast<const f16x8*>(ub + nl * 8);
            const f16* wp = wb + (size_t)nl * 1280;
            float t[10];
            #pragma unroll
            for (int m = 0; m < 10; ++m) {
                const f16x8 af = *reinterpret_cast<const f16x8*>(wp + m * 128);
                f32x4 C = __builtin_amdgcn_mfma_f32_16x16x32_f16(af, bf, cz, 0, 0, 0);
                t[m] = fmaf(A4[m][0], C[0], A4[m][1] * C[1]) +
                       fmaf(A4[m][2], C[2], A4[m][3] * C[3]);
            }
            #pragma unroll
            for (int m = 0; m < 10; ++m) t[m] += __shfl_xor(t[m], 16, 64);
            #pragma unroll
            for (int m = 0; m < 10; ++m) t[m] += __shfl_xor(t[m], 32, 64);
            float mx = fmaxf(fmaxf(fmaxf(fmaxf(t[0], t[1]), fmaxf(t[2], t[3])),
                                   fmaxf(fmaxf(t[4], t[5]), fmaxf(t[6], t[7]))),
                             fmaxf(t[8], t[9]));
            float sum = 0.f;
            #pragma unroll
            for (int m = 0; m < 10; ++m) { float e = __expf(t[m] - mx); c[nl][m] = e; sum += e; }
            const float inv = 1.0f / sum;
            #pragma unroll
            for (int m = 0; m < 10; ++m) c[nl][m] *= inv;
        }
    }

    f32x4 P[10];
    #pragma unroll
    for (int m = 0; m < 10; ++m) P[m] = cz;

    #pragma unroll
    for (int nl = 0; nl < 4; ++nl) {
        const f16x8 bf = *reinterpret_cast<const f16x8*>(ub + nl * 8);
        const f16* wp = wb + (size_t)nl * 1280;
        #pragma unroll
        for (int m = 0; m < 10; ++m) {
            const f16x8 af = *reinterpret_cast<const f16x8*>(wp + m * 128);
            if (FIRST) {
                P[m] = __builtin_amdgcn_mfma_f32_16x16x32_f16(af, bf, P[m], 0, 0, 0);
            } else {
                f32x4 C = __builtin_amdgcn_mfma_f32_16x16x32_f16(af, bf, cz, 0, 0, 0);
                const float cc = c[nl][m];
                #pragma unroll
                for (int i = 0; i < 4; ++i) P[m][i] = fmaf(cc, C[i], P[m][i]);
            }
        }
    }

    // cross-wave reduce (the 4 waves cover different n) then one store per block
    #pragma unroll
    for (int m = 0; m < 10; ++m)
        *reinterpret_cast<f32x4*>(&s1t[w][col][m * 16 + kg * 4]) = P[m];
    __syncthreads();
    for (int r = tid; r < 2560; r += 256) {
        const int row = r / 160, slot = r - row * 160;
        float v = s1t[0][row][slot] + s1t[1][row][slot] + s1t[2][row][slot] + s1t[3][row][slot];
        partial[((size_t)chunk * 128 + bg * 16 + row) * 160 + slot] = v;
    }
}

// ---- reduce 288 chunk-partials, squash, update A-state / write out.
// slot k = j*16 + o.  Ar stores 0.25*Sum(s).  out[b][o*10+j].
template<int MODE>   // 0: Ar = s/4   1: Ar += s/4   2: out = s
__global__ __launch_bounds__(640) void phase2(const float* __restrict__ partial,
                                              float* __restrict__ Ar, float* __restrict__ out,
                                              float sumscale) {
    const int b = blockIdx.x, k = threadIdx.x, y = threadIdx.y;
    __shared__ float sr4[4][160];
    __shared__ float srs[160];
    float a = 0.f;
    for (int c = y; c < 288; c += 4)
        a += partial[((size_t)c * 128 + b) * 160 + k];
    sr4[y][k] = a;
    __syncthreads();
    if (y == 0)
        srs[k] = (sr4[0][k] + sr4[1][k] + sr4[2][k] + sr4[3][k]) * sumscale;
    __syncthreads();
    if (y == 0) {
        const int j = k >> 4;
        float ssq = 0.f;
        #pragma unroll
        for (int o = 0; o < 16; ++o) { float v = srs[j * 16 + o]; ssq = fmaf(v, v, ssq); }
        const float s = srs[k] * ssq / ((1.f + ssq) * sqrtf(ssq));
        if (MODE == 0)      Ar[(size_t)b * 160 + k] = 0.25f * s;
        else if (MODE == 1) Ar[(size_t)b * 160 + k] += 0.25f * s;
        else { const int o = k & 15; out[(size_t)b * 160 + o * 10 + j] = s; }
    }
}

extern "C" void kernel_launch(void* const* d_in, const int* in_sizes, int n_in,
                              void* d_out, int out_size, void* d_ws, size_t ws_size,
                              hipStream_t stream) {
    const float* x = (const float*)d_in[0];   // (128, 8, 32, 12, 12)
    const float* W = (const float*)d_in[1];   // (8, 16, 4608, 10)
    float* out = (float*)d_out;               // (128, 16, 10)

    f16* ut = (f16*)d_ws;                                   // 128*4608*8 h    = 9.4 MB
    f16* wt = ut + (size_t)128 * NTOT * 8;                  // 4608*160*8 h    = 11.8 MB
    float* Ar = (float*)(wt + (size_t)NTOT * 160 * 8);      // 128*160 f32
    float* partial = Ar + 128 * 160;                        // 288*128*160 f32 = 23.6 MB

    make_ut<<<2304, 256, 0, stream>>>(x, ut);
    make_wt<<<2304, 320, 0, stream>>>(W, wt);

    dim3 gR(288, 8), b2(160, 4);
    routing<true ><<<gR, 256, 0, stream>>>(ut, wt, Ar, partial);
    phase2<0><<<128, b2, 0, stream>>>(partial, Ar, out, 0.025f);   // 0.1 (c0) * 0.25 (K-dup)
    routing<false><<<gR, 256, 0, stream>>>(ut, wt, Ar, partial);
    phase2<1><<<128, b2, 0, stream>>>(partial, Ar, out, 0.25f);
    routing<false><<<gR, 256, 0, stream>>>(ut, wt, Ar, partial);
    phase2<2><<<128, b2, 0, stream>>>(partial, Ar, out, 0.25f);
}

// Round 6
// 174.644 us; speedup vs baseline: 1.7581x; 1.7581x over previous
//
#include <hip/hip_runtime.h>
#include <math.h>

#define NTOT 4608          // N_IN * DIM * DIM

typedef _Float16 f16;
typedef _Float16 f16x4 __attribute__((ext_vector_type(4)));
typedef _Float16 f16x8 __attribute__((ext_vector_type(8)));
typedef float f32x4 __attribute__((ext_vector_type(4)));

// ---- ut[b][n][d] f16 <- x[b][d][n] f32
__global__ __launch_bounds__(256) void make_ut(const float* __restrict__ x, f16* __restrict__ ut) {
    const int t = blockIdx.x * 256 + threadIdx.x;     // b*4608 + n
    const int b = t / NTOT, n = t - b * NTOT;
    f16x8 v;
    #pragma unroll
    for (int d = 0; d < 8; ++d)
        v[d] = (f16)x[((size_t)b * 8 + d) * NTOT + n];
    *reinterpret_cast<f16x8*>(ut + (size_t)t * 8) = v;
}

// ---- wt[n][j*16+o][d] f16 <- W[d][o][n][j] f32, LDS-staged for coalescing.
__global__ __launch_bounds__(320) void make_wt(const float* __restrict__ W, f16* __restrict__ wt) {
    __shared__ float l[2560];
    const int k = threadIdx.x;           // 0..319
    const int n0 = blockIdx.x * 2;
    #pragma unroll
    for (int r = 0; r < 8; ++r) {
        const int f = k + r * 320;
        const int p = f / 20, q = f - p * 20;
        l[f] = W[(size_t)p * 46080 + n0 * 10 + q];
    }
    __syncthreads();
    const int half = k / 160, rr = k - half * 160;    // rr = j*16 + o
    const int j = rr >> 4, o = rr & 15;
    f16x8 v;
    #pragma unroll
    for (int d = 0; d < 8; ++d)
        v[d] = (f16)l[d * 320 + o * 20 + half * 10 + j];
    *reinterpret_cast<f16x8*>(wt + ((size_t)(n0 + half) * 160 + rr) * 8) = v;
}

// ---- kernelA: materialize u_hat (f16, layout [n][sg=0..19][b][8 halves]) + iter-0 partials.
// grid (144, 8). Wave w: n = chunk*32 + w*8 .. +8, 16 b. K-dup MFMA -> C = 4*u_hat.
// Lane (col = b-local, qA): C[m][i] = 4*uh[b][n][slot = m*16 + qA*4 + i].
// Store f16x4(0.25*C) at chunk sg = 2m + (qA>>1), inner (qA&1)*4.
__global__ __launch_bounds__(256) void kernelA(const f16* __restrict__ ut, const f16* __restrict__ wt,
                                               f16* __restrict__ uh, float* __restrict__ partial) {
    __shared__ float s0t[4][16][164];
    const int tid = threadIdx.x, w = tid >> 6, lane = tid & 63;
    const int col = lane & 15, qA = lane >> 4;
    const int chunk = blockIdx.x, bg = blockIdx.y, b0 = bg * 16;
    const int b = b0 + col;
    const int nstart = chunk * 32 + w * 8;

    const f16* ab = wt + ((size_t)nstart * 160 + col) * 8;
    const f16* ub = ut + ((size_t)b * NTOT + nstart) * 8;
    f16* uhw = uh + (size_t)nstart * 20480 + (size_t)(qA >> 1) * 1024 + b * 8 + (qA & 1) * 4;

    const f32x4 cz = {0.f, 0.f, 0.f, 0.f};
    f32x4 s0a[10];
    #pragma unroll
    for (int m = 0; m < 10; ++m) s0a[m] = cz;

    for (int nl = 0; nl < 8; ++nl) {
        const f16x8 bf = *reinterpret_cast<const f16x8*>(ub + nl * 8);
        #pragma unroll
        for (int m = 0; m < 10; ++m) {
            const f16x8 af = *reinterpret_cast<const f16x8*>(ab + ((size_t)nl * 160 + m * 16) * 8);
            f32x4 C = __builtin_amdgcn_mfma_f32_16x16x32_f16(af, bf, cz, 0, 0, 0);
            s0a[m] += C;
            f16x4 hv;
            hv[0] = (f16)(0.25f * C[0]); hv[1] = (f16)(0.25f * C[1]);
            hv[2] = (f16)(0.25f * C[2]); hv[3] = (f16)(0.25f * C[3]);
            *reinterpret_cast<f16x4*>(uhw + (size_t)nl * 20480 + m * 2048) = hv;
        }
    }

    #pragma unroll
    for (int m = 0; m < 10; ++m)
        *reinterpret_cast<f32x4*>(&s0t[w][col][m * 16 + qA * 4]) = s0a[m];
    __syncthreads();
    for (int r = tid; r < 2560; r += 256) {
        const int row = r / 160, slot = r - row * 160;
        float v = s0t[0][row][slot] + s0t[1][row][slot] + s0t[2][row][slot] + s0t[3][row][slot];
        partial[((size_t)chunk * 128 + b0 + row) * 160 + slot] = v;
    }
}

// ---- kernelB: one routing iteration from materialized u_hat.
// grid (288, 8). Wave w: n = chunk*16 + w*4 .. +4, lanes: g = lane&15 (b-local, FAST
// for coalescing), q = lane>>4 (sg-quad). Lane's 5 chunks: sg = 4s+q -> j = sg>>1,
// slots [sg*8, sg*8+8). Logit reduce: shfl_xor 16 (o-halves) + 32 (j parity swap).
__global__ __launch_bounds__(256) void kernelB(const f16* __restrict__ uh, const float* __restrict__ Ar,
                                               float* __restrict__ partial) {
    __shared__ float s1t[4][16][164];
    const int tid = threadIdx.x, w = tid >> 6, lane = tid & 63;
    const int g = lane & 15, q = lane >> 4;
    const int chunk = blockIdx.x, bg = blockIdx.y;
    const int b = bg * 16 + g;
    const int nstart = chunk * 16 + w * 4;
    const bool qlow = (q < 2);

    float Af[5][8];
    #pragma unroll
    for (int s = 0; s < 5; ++s) {
        f32x4 a0 = *reinterpret_cast<const f32x4*>(Ar + (size_t)b * 160 + (4 * s + q) * 8);
        f32x4 a1 = *reinterpret_cast<const f32x4*>(Ar + (size_t)b * 160 + (4 * s + q) * 8 + 4);
        #pragma unroll
        for (int t = 0; t < 4; ++t) { Af[s][t] = a0[t]; Af[s][4 + t] = a1[t]; }
    }

    float P[5][8];
    #pragma unroll
    for (int s = 0; s < 5; ++s)
        #pragma unroll
        for (int t = 0; t < 8; ++t) P[s][t] = 0.f;

    const f16* uhb = uh + (size_t)nstart * 20480 + (size_t)q * 1024 + b * 8;

    for (int nl = 0; nl < 4; ++nl) {
        f16x8 U[5];
        #pragma unroll
        for (int s = 0; s < 5; ++s)
            U[s] = *reinterpret_cast<const f16x8*>(uhb + (size_t)nl * 20480 + s * 4096);

        float tp[5];
        #pragma unroll
        for (int s = 0; s < 5; ++s) {
            float acc = 0.f;
            #pragma unroll
            for (int t = 0; t < 8; ++t)
                acc = fmaf(Af[s][t], (float)U[s][t], acc);
            tp[s] = acc;
        }

        float tt[10];
        #pragma unroll
        for (int s = 0; s < 5; ++s) {
            float tq = tp[s] + __shfl_xor(tp[s], 16, 64);
            float tr = __shfl_xor(tq, 32, 64);
            tt[2 * s]     = qlow ? tq : tr;
            tt[2 * s + 1] = qlow ? tr : tq;
        }

        float mx = fmaxf(fmaxf(fmaxf(fmaxf(tt[0], tt[1]), fmaxf(tt[2], tt[3])),
                               fmaxf(fmaxf(tt[4], tt[5]), fmaxf(tt[6], tt[7]))),
                         fmaxf(tt[8], tt[9]));
        float c[10], sum = 0.f;
        #pragma unroll
        for (int j = 0; j < 10; ++j) { float e = __expf(tt[j] - mx); c[j] = e; sum += e; }
        const float inv = 1.0f / sum;

        #pragma unroll
        for (int s = 0; s < 5; ++s) {
            const float cm = (qlow ? c[2 * s] : c[2 * s + 1]) * inv;
            #pragma unroll
            for (int t = 0; t < 8; ++t)
                P[s][t] = fmaf(cm, (float)U[s][t], P[s][t]);
        }
    }

    #pragma unroll
    for (int s = 0; s < 5; ++s) {
        const int sg = 4 * s + q;
        f32x4 p0 = {P[s][0], P[s][1], P[s][2], P[s][3]};
        f32x4 p1 = {P[s][4], P[s][5], P[s][6], P[s][7]};
        *reinterpret_cast<f32x4*>(&s1t[w][g][sg * 8])     = p0;
        *reinterpret_cast<f32x4*>(&s1t[w][g][sg * 8 + 4]) = p1;
    }
    __syncthreads();
    for (int r = tid; r < 2560; r += 256) {
        const int row = r / 160, slot = r - row * 160;
        float v = s1t[0][row][slot] + s1t[1][row][slot] + s1t[2][row][slot] + s1t[3][row][slot];
        partial[((size_t)chunk * 128 + bg * 16 + row) * 160 + slot] = v;
    }
}

// ---- red1: partial[nchunk][128][160] -> p2[b][8][160] (slice-sums)
__global__ __launch_bounds__(160) void red1(const float* __restrict__ partial,
                                            float* __restrict__ p2, int nc8) {
    const int b = blockIdx.x, sl = blockIdx.y, k = threadIdx.x;
    const float* p = partial + ((size_t)sl * nc8 * 128 + b) * 160 + k;
    float acc = 0.f;
    for (int c = 0; c < nc8; ++c) acc += p[(size_t)c * 128 * 160];
    p2[((size_t)b * 8 + sl) * 160 + k] = acc;
}

// ---- phase2f: finish sum, squash, update A-state / write out. slot k = j*16 + o.
template<int MODE>   // 0: Ar = s   1: Ar += s   2: out = s
__global__ __launch_bounds__(160) void phase2f(const float* __restrict__ p2,
                                               float* __restrict__ Ar, float* __restrict__ out,
                                               float sumscale) {
    const int b = blockIdx.x, k = threadIdx.x;
    __shared__ float srs[160];
    float acc = 0.f;
    #pragma unroll
    for (int sl = 0; sl < 8; ++sl) acc += p2[((size_t)b * 8 + sl) * 160 + k];
    acc *= sumscale;
    srs[k] = acc;
    __syncthreads();
    const int j = k >> 4;
    float ssq = 0.f;
    #pragma unroll
    for (int o = 0; o < 16; ++o) { float v = srs[j * 16 + o]; ssq = fmaf(v, v, ssq); }
    const float s = acc * ssq / ((1.f + ssq) * sqrtf(ssq));
    if (MODE == 0)      Ar[(size_t)b * 160 + k] = s;
    else if (MODE == 1) Ar[(size_t)b * 160 + k] += s;
    else { const int o = k & 15; out[(size_t)b * 160 + o * 10 + j] = s; }
}

extern "C" void kernel_launch(void* const* d_in, const int* in_sizes, int n_in,
                              void* d_out, int out_size, void* d_ws, size_t ws_size,
                              hipStream_t stream) {
    const float* x = (const float*)d_in[0];   // (128, 8, 32, 12, 12)
    const float* W = (const float*)d_in[1];   // (8, 16, 4608, 10)
    float* out = (float*)d_out;               // (128, 16, 10)

    f16* ut = (f16*)d_ws;                                   // 128*4608*8 h     = 9.4 MB
    f16* wt = ut + (size_t)128 * NTOT * 8;                  // 4608*160*8 h     = 11.8 MB
    f16* uh = wt + (size_t)NTOT * 160 * 8;                  // 4608*20*128*8 h  = 188.7 MB
    float* Ar = (float*)(uh + (size_t)NTOT * 20 * 128 * 8); // 128*160 f32
    float* partial = Ar + 128 * 160;                        // 288*128*160 f32  = 23.6 MB
    float* p2 = partial + (size_t)288 * 128 * 160;          // 128*8*160 f32    = 0.65 MB

    make_ut<<<2304, 256, 0, stream>>>(x, ut);
    make_wt<<<2304, 320, 0, stream>>>(W, wt);

    dim3 gA(144, 8), gB(288, 8), gR(128, 8);
    kernelA<<<gA, 256, 0, stream>>>(ut, wt, uh, partial);
    red1<<<gR, 160, 0, stream>>>(partial, p2, 144 / 8);
    phase2f<0><<<128, 160, 0, stream>>>(p2, Ar, out, 0.025f);   // 0.1 (c0) * 0.25 (K-dup)

    kernelB<<<gB, 256, 0, stream>>>(uh, Ar, partial);
    red1<<<gR, 160, 0, stream>>>(partial, p2, 288 / 8);
    phase2f<1><<<128, 160, 0, stream>>>(p2, Ar, out, 1.0f);

    kernelB<<<gB, 256, 0, stream>>>(uh, Ar, partial);
    red1<<<gR, 160, 0, stream>>>(partial, p2, 288 / 8);
    phase2f<2><<<128, 160, 0, stream>>>(p2, Ar, out, 1.0f);
}

// Round 7
// 165.954 us; speedup vs baseline: 1.8501x; 1.0524x over previous
//
#include <hip/hip_runtime.h>
#include <math.h>

#define NTOT 4608          // N_IN * DIM * DIM

typedef _Float16 f16;
typedef _Float16 f16x4 __attribute__((ext_vector_type(4)));
typedef _Float16 f16x8 __attribute__((ext_vector_type(8)));
typedef float f32x4 __attribute__((ext_vector_type(4)));

// ---- prep: blockIdx < 2304 -> wt[n][j*16+o][d] f16 (LDS-staged transpose of W)
//            blockIdx >= 2304 -> ut[b][n][d] f16 <- x[b][d][n]
__global__ __launch_bounds__(320) void prep(const float* __restrict__ x, const float* __restrict__ W,
                                            f16* __restrict__ ut, f16* __restrict__ wt) {
    __shared__ float l[2560];
    const int k = threadIdx.x;           // 0..319
    if (blockIdx.x < 2304) {
        const int n0 = blockIdx.x * 2;
        #pragma unroll
        for (int r = 0; r < 8; ++r) {
            const int f = k + r * 320;
            const int p = f / 20, q = f - p * 20;
            l[f] = W[(size_t)p * 46080 + n0 * 10 + q];
        }
        __syncthreads();
        const int half = k / 160, rr = k - half * 160;    // rr = j*16 + o
        const int j = rr >> 4, o = rr & 15;
        f16x8 v;
        #pragma unroll
        for (int d = 0; d < 8; ++d)
            v[d] = (f16)l[d * 320 + o * 20 + half * 10 + j];
        *reinterpret_cast<f16x8*>(wt + ((size_t)(n0 + half) * 160 + rr) * 8) = v;
    } else {
        const int t = (blockIdx.x - 2304) * 320 + k;      // b*4608 + n
        if (t < 128 * NTOT) {
            const int b = t / NTOT, n = t - b * NTOT;
            f16x8 v;
            #pragma unroll
            for (int d = 0; d < 8; ++d)
                v[d] = (f16)x[((size_t)b * 8 + d) * NTOT + n];
            *reinterpret_cast<f16x8*>(ut + (size_t)t * 8) = v;
        }
    }
}

// ---- kernelA: materialize u_hat (f16, layout [n][sg=0..19][b][8 halves]) + iter-0 partials.
// grid (144, 8). Wave w: n = chunk*32 + w*8 .. +8, 16 b. K-dup MFMA -> C = 4*u_hat.
// Store f16x4(0.25*C): true uh. Partial carries 4x (sumscale 0.025 = 0.1*0.25).
__global__ __launch_bounds__(256) void kernelA(const f16* __restrict__ ut, const f16* __restrict__ wt,
                                               f16* __restrict__ uh, float* __restrict__ partial) {
    __shared__ float s0t[4][16][164];
    const int tid = threadIdx.x, w = tid >> 6, lane = tid & 63;
    const int col = lane & 15, qA = lane >> 4;
    const int chunk = blockIdx.x, bg = blockIdx.y, b0 = bg * 16;
    const int b = b0 + col;
    const int nstart = chunk * 32 + w * 8;

    const f16* ab = wt + ((size_t)nstart * 160 + col) * 8;
    const f16* ub = ut + ((size_t)b * NTOT + nstart) * 8;
    f16* uhw = uh + (size_t)nstart * 20480 + (size_t)(qA >> 1) * 1024 + b * 8 + (qA & 1) * 4;

    const f32x4 cz = {0.f, 0.f, 0.f, 0.f};
    f32x4 s0a[10];
    #pragma unroll
    for (int m = 0; m < 10; ++m) s0a[m] = cz;

    for (int nl = 0; nl < 8; ++nl) {
        const f16x8 bf = *reinterpret_cast<const f16x8*>(ub + nl * 8);
        #pragma unroll
        for (int m = 0; m < 10; ++m) {
            const f16x8 af = *reinterpret_cast<const f16x8*>(ab + ((size_t)nl * 160 + m * 16) * 8);
            f32x4 C = __builtin_amdgcn_mfma_f32_16x16x32_f16(af, bf, cz, 0, 0, 0);
            s0a[m] += C;
            f16x4 hv;
            hv[0] = (f16)(0.25f * C[0]); hv[1] = (f16)(0.25f * C[1]);
            hv[2] = (f16)(0.25f * C[2]); hv[3] = (f16)(0.25f * C[3]);
            *reinterpret_cast<f16x4*>(uhw + (size_t)nl * 20480 + m * 2048) = hv;
        }
    }

    #pragma unroll
    for (int m = 0; m < 10; ++m)
        *reinterpret_cast<f32x4*>(&s0t[w][col][m * 16 + qA * 4]) = s0a[m];
    __syncthreads();
    for (int r = tid; r < 2560; r += 256) {
        const int row = r / 160, slot = r - row * 160;
        float v = s0t[0][row][slot] + s0t[1][row][slot] + s0t[2][row][slot] + s0t[3][row][slot];
        partial[((size_t)chunk * 128 + b0 + row) * 160 + slot] = v;
    }
}

// ---- kernelB: one routing iteration from materialized u_hat.
// grid (144, 8). Wave w: n = chunk*32 + w*8 .. +8. Lanes: g = lane&15 (b-local, fast),
// q = lane>>4 (sg-quad). Lane's 5 chunks: sg = 4s+q -> j = sg>>1, slots [sg*8, sg*8+8).
// Logit reduce: shfl_xor 16 (o-halves) + 32 (j parity swap).
__global__ __launch_bounds__(256) void kernelB(const f16* __restrict__ uh, const float* __restrict__ Ar,
                                               float* __restrict__ partial) {
    __shared__ float s1t[4][16][164];
    const int tid = threadIdx.x, w = tid >> 6, lane = tid & 63;
    const int g = lane & 15, q = lane >> 4;
    const int chunk = blockIdx.x, bg = blockIdx.y;
    const int b = bg * 16 + g;
    const int nstart = chunk * 32 + w * 8;
    const bool qlow = (q < 2);

    float Af[5][8];
    #pragma unroll
    for (int s = 0; s < 5; ++s) {
        f32x4 a0 = *reinterpret_cast<const f32x4*>(Ar + (size_t)b * 160 + (4 * s + q) * 8);
        f32x4 a1 = *reinterpret_cast<const f32x4*>(Ar + (size_t)b * 160 + (4 * s + q) * 8 + 4);
        #pragma unroll
        for (int t = 0; t < 4; ++t) { Af[s][t] = a0[t]; Af[s][4 + t] = a1[t]; }
    }

    float P[5][8];
    #pragma unroll
    for (int s = 0; s < 5; ++s)
        #pragma unroll
        for (int t = 0; t < 8; ++t) P[s][t] = 0.f;

    const f16* uhb = uh + (size_t)nstart * 20480 + (size_t)q * 1024 + b * 8;

    for (int nl = 0; nl < 8; ++nl) {
        f16x8 U[5];
        #pragma unroll
        for (int s = 0; s < 5; ++s)
            U[s] = *reinterpret_cast<const f16x8*>(uhb + (size_t)nl * 20480 + s * 4096);

        float tp[5];
        #pragma unroll
        for (int s = 0; s < 5; ++s) {
            float acc = 0.f;
            #pragma unroll
            for (int t = 0; t < 8; ++t)
                acc = fmaf(Af[s][t], (float)U[s][t], acc);
            tp[s] = acc;
        }

        float tt[10];
        #pragma unroll
        for (int s = 0; s < 5; ++s) {
            float tq = tp[s] + __shfl_xor(tp[s], 16, 64);
            float tr = __shfl_xor(tq, 32, 64);
            tt[2 * s]     = qlow ? tq : tr;
            tt[2 * s + 1] = qlow ? tr : tq;
        }

        float mx = fmaxf(fmaxf(fmaxf(fmaxf(tt[0], tt[1]), fmaxf(tt[2], tt[3])),
                               fmaxf(fmaxf(tt[4], tt[5]), fmaxf(tt[6], tt[7]))),
                         fmaxf(tt[8], tt[9]));
        float c[10], sum = 0.f;
        #pragma unroll
        for (int j = 0; j < 10; ++j) { float e = __expf(tt[j] - mx); c[j] = e; sum += e; }
        const float inv = 1.0f / sum;

        #pragma unroll
        for (int s = 0; s < 5; ++s) {
            const float cm = (qlow ? c[2 * s] : c[2 * s + 1]) * inv;
            #pragma unroll
            for (int t = 0; t < 8; ++t)
                P[s][t] = fmaf(cm, (float)U[s][t], P[s][t]);
        }
    }

    #pragma unroll
    for (int s = 0; s < 5; ++s) {
        const int sg = 4 * s + q;
        f32x4 p0 = {P[s][0], P[s][1], P[s][2], P[s][3]};
        f32x4 p1 = {P[s][4], P[s][5], P[s][6], P[s][7]};
        *reinterpret_cast<f32x4*>(&s1t[w][g][sg * 8])     = p0;
        *reinterpret_cast<f32x4*>(&s1t[w][g][sg * 8 + 4]) = p1;
    }
    __syncthreads();
    for (int r = tid; r < 2560; r += 256) {
        const int row = r / 160, slot = r - row * 160;
        float v = s1t[0][row][slot] + s1t[1][row][slot] + s1t[2][row][slot] + s1t[3][row][slot];
        partial[((size_t)chunk * 128 + bg * 16 + row) * 160 + slot] = v;
    }
}

// ---- reduce_squash: sum 144 chunk-partials, squash, update A-state / write out.
// 128 blocks x 640 threads; k = slot (j*16+o), r = chunk-stripe 0..3.
template<int MODE>   // 0: Ar = s   1: Ar += s   2: out = s
__global__ __launch_bounds__(640) void reduce_squash(const float* __restrict__ partial,
                                                     float* __restrict__ Ar, float* __restrict__ out,
                                                     float sumscale) {
    const int b = blockIdx.x;
    const int k = threadIdx.x % 160;
    const int r = threadIdx.x / 160;     // 0..3
    __shared__ float red[4][160];
    float acc = 0.f;
    for (int c = r; c < 144; c += 4)
        acc += partial[((size_t)c * 128 + b) * 160 + k];
    red[r][k] = acc;
    __syncthreads();
    if (r == 0) {
        float a = (red[0][k] + red[1][k] + red[2][k] + red[3][k]) * sumscale;
        red[0][k] = a;
        __syncthreads();
        const int j = k >> 4;
        float ssq = 0.f;
        #pragma unroll
        for (int o = 0; o < 16; ++o) { float v = red[0][j * 16 + o]; ssq = fmaf(v, v, ssq); }
        const float s = a * ssq / ((1.f + ssq) * sqrtf(ssq));
        if (MODE == 0)      Ar[(size_t)b * 160 + k] = s;
        else if (MODE == 1) Ar[(size_t)b * 160 + k] += s;
        else { const int o = k & 15; out[(size_t)b * 160 + o * 10 + j] = s; }
    } else {
        __syncthreads();   // keep barrier uniform across the block
    }
}

extern "C" void kernel_launch(void* const* d_in, const int* in_sizes, int n_in,
                              void* d_out, int out_size, void* d_ws, size_t ws_size,
                              hipStream_t stream) {
    const float* x = (const float*)d_in[0];   // (128, 8, 32, 12, 12)
    const float* W = (const float*)d_in[1];   // (8, 16, 4608, 10)
    float* out = (float*)d_out;               // (128, 16, 10)

    f16* ut = (f16*)d_ws;                                   // 128*4608*8 h     = 9.4 MB
    f16* wt = ut + (size_t)128 * NTOT * 8;                  // 4608*160*8 h     = 11.8 MB
    f16* uh = wt + (size_t)NTOT * 160 * 8;                  // 4608*20*128*8 h  = 188.7 MB
    float* Ar = (float*)(uh + (size_t)NTOT * 20 * 128 * 8); // 128*160 f32
    float* partial = Ar + 128 * 160;                        // 144*128*160 f32  = 11.8 MB

    prep<<<2304 + 1844, 320, 0, stream>>>(x, W, ut, wt);

    dim3 gA(144, 8);
    kernelA<<<gA, 256, 0, stream>>>(ut, wt, uh, partial);
    reduce_squash<0><<<128, 640, 0, stream>>>(partial, Ar, out, 0.025f);  // 0.1 (c0) * 0.25 (K-dup)

    kernelB<<<gA, 256, 0, stream>>>(uh, Ar, partial);
    reduce_squash<1><<<128, 640, 0, stream>>>(partial, Ar, out, 1.0f);

    kernelB<<<gA, 256, 0, stream>>>(uh, Ar, partial);
    reduce_squash<2><<<128, 640, 0, stream>>>(partial, Ar, out, 1.0f);
}